// Round 5
// baseline (181.550 us; speedup 1.0000x reference)
//
#include <hip/hip_runtime.h>
#include <hip/hip_bf16.h>

// Bloom MLP fused: h=X@W1^T+b1; g=gelu_tanh(h); out=g@W2^T+b2+residual
// X:[262144,64] f32, W1:[256,64], W2:[64,256], out:[262144,64] f32.
//
// Round 5: occupancy push. 32-token tiles (Gs = 16.9KB -> 8-9 blocks/CU by
// LDS), __launch_bounds__(256,6) (<=85 VGPR -> 6 blocks/CU), w2f reloaded
// per tile (pre-barrier, L1-hot), R loaded in epilogue (TLP hides it),
// exp2-direct GELU. Structure per tile: GEMM1 -> Gs -> barrier -> GEMM2.

typedef __attribute__((ext_vector_type(8))) short bf16x8;   // MFMA A/B frag
typedef __attribute__((ext_vector_type(4))) float f32x4;    // MFMA C/D frag
typedef __attribute__((ext_vector_type(4))) short short4v;  // packed 4x bf16

#define NBLK  4096
#define TILES 2      // 4096 blocks * 2 tiles * 32 tokens = 262144

__device__ __forceinline__ short f2bf(float x) {
    union { __hip_bfloat16 h; short s; } u;
    u.h = __float2bfloat16(x);      // compiler pairs into v_cvt_pk_bf16_f32
    return u.s;
}

__device__ __forceinline__ float bloom_gelu(float x) {
    // 0.5*x*(1+tanh(0.79788456*(x+0.044715*x^3))) = x*(1 - 1/(e^{2u}+1))
    // 2u*log2(e) = 2.30220842*x + 0.10294325*x^3  -> v_exp_f32 (2^x) direct
    float x2 = x * x;
    float t1 = __builtin_fmaf(0.10294325f, x2, 2.30220842f);
    float e  = __builtin_exp2f(x * t1);
    float r  = __builtin_amdgcn_rcpf(e + 1.0f);
    return x - x * r;
}

// ---- pre-pass: convert W1 (16384 f32) then W2 (16384 f32) to bf16 in ws ----
__global__ __launch_bounds__(256) void cvt_weights(
    const float* __restrict__ W1, const float* __restrict__ W2,
    short* __restrict__ wsb)
{
    const int i4 = (blockIdx.x * 256 + threadIdx.x) * 4;   // 0..32764, step 4
    const float* src = (i4 < 16384) ? (W1 + i4) : (W2 + (i4 - 16384));
    float4 v = *(const float4*)src;
    short4v o;
    o[0] = f2bf(v.x); o[1] = f2bf(v.y); o[2] = f2bf(v.z); o[3] = f2bf(v.w);
    *(short4v*)(wsb + i4) = o;
}

template<bool PRE>
__global__ __launch_bounds__(256, 6) void bloom_mlp(
    const float* __restrict__ X,  const float* __restrict__ R,
    const float* __restrict__ W1, const float* __restrict__ b1,
    const float* __restrict__ W2, const float* __restrict__ b2,
    const short* __restrict__ Wb, float* __restrict__ out)
{
    // G[token][f] bf16, 32 tokens, row stride 264 (528B): ds_write_b64 at
    // 4 acc/bank, ds_read_b128 at 8 acc/bank -- both the width minimum.
    __shared__ __align__(16) short Gs[32][264];

    const int tid  = threadIdx.x;
    const int wid  = tid >> 6;      // wave 0..3
    const int lane = tid & 63;
    const int q    = lane >> 4;     // 0..3
    const int c    = lane & 15;     // 0..15
    const int f0   = wid << 6;      // GEMM1 f-slice base

    // ---- W1 fragments, register-resident across tiles ----
    // lane holds W1[f0+16t+c][kb*32+q*8..+7]
    bf16x8 w1f[4][2];
    if constexpr (PRE) {
        const short* W1b = Wb;
#pragma unroll
        for (int t = 0; t < 4; ++t)
#pragma unroll
            for (int kb = 0; kb < 2; ++kb)
                w1f[t][kb] = *(const bf16x8*)&W1b[(f0 + 16*t + c) * 64 + kb*32 + q*8];
    } else {
#pragma unroll
        for (int t = 0; t < 4; ++t)
#pragma unroll
            for (int kb = 0; kb < 2; ++kb) {
                const float* p = W1 + (size_t)(f0 + 16*t + c) * 64 + kb*32 + q*8;
                float4 lo = *(const float4*)p, hi = *(const float4*)(p + 4);
                bf16x8 f;
                f[0]=f2bf(lo.x); f[1]=f2bf(lo.y); f[2]=f2bf(lo.z); f[3]=f2bf(lo.w);
                f[4]=f2bf(hi.x); f[5]=f2bf(hi.y); f[6]=f2bf(hi.z); f[7]=f2bf(hi.w);
                w1f[t][kb] = f;
            }
    }

    const float4 b2q = *(const float4*)(b2 + 16*wid + 4*q);

    for (int it = 0; it < TILES; ++it) {
        const int row0 = (blockIdx.x * TILES + it) << 5;   // 32 tokens/tile

        // ---- GEMM1 + GELU -> Gs (m = 2 token sub-tiles of 16) ----
#pragma unroll
        for (int m = 0; m < 2; ++m) {
            bf16x8 a1[2];   // B-op: lane holds X[row0+16m+c][kb*32+q*8..+7]
#pragma unroll
            for (int kb = 0; kb < 2; ++kb) {
                const float* p = X + (size_t)(row0 + 16*m + c) * 64 + kb*32 + q*8;
                float4 lo = *(const float4*)p, hi = *(const float4*)(p + 4);
                bf16x8 f;
                f[0]=f2bf(lo.x); f[1]=f2bf(lo.y); f[2]=f2bf(lo.z); f[3]=f2bf(lo.w);
                f[4]=f2bf(hi.x); f[5]=f2bf(hi.y); f[6]=f2bf(hi.z); f[7]=f2bf(hi.w);
                a1[kb] = f;
            }
            // D[f_local=4q+r][token=c] per f-tile t
#pragma unroll
            for (int t = 0; t < 4; ++t) {
                const float4 b1q = *(const float4*)(b1 + f0 + 16*t + 4*q);
                f32x4 acc = {0.f, 0.f, 0.f, 0.f};
                acc = __builtin_amdgcn_mfma_f32_16x16x32_bf16(w1f[t][0], a1[0], acc, 0, 0, 0);
                acc = __builtin_amdgcn_mfma_f32_16x16x32_bf16(w1f[t][1], a1[1], acc, 0, 0, 0);
                short4v g;
#pragma unroll
                for (int r = 0; r < 4; ++r)
                    g[r] = f2bf(bloom_gelu(acc[r] + b1q[r]));
                *(short4v*)&Gs[16*m + c][f0 + 16*t + 4*q] = g;   // 8B packed
            }
        }

        // ---- W2 fragments for this wave's d-tile (reloaded per tile;
        //      issued pre-barrier so loads fly under the barrier; L1-hot) ----
        bf16x8 w2f[8];
        if constexpr (PRE) {
            const short* W2b = Wb + 16384;
#pragma unroll
            for (int kb = 0; kb < 8; ++kb)
                w2f[kb] = *(const bf16x8*)&W2b[(16*wid + c) * 256 + kb*32 + q*8];
        } else {
#pragma unroll
            for (int kb = 0; kb < 8; ++kb) {
                const float* p = W2 + (size_t)(16*wid + c) * 256 + kb*32 + q*8;
                float4 lo = *(const float4*)p, hi = *(const float4*)(p + 4);
                bf16x8 f;
                f[0]=f2bf(lo.x); f[1]=f2bf(lo.y); f[2]=f2bf(lo.z); f[3]=f2bf(lo.w);
                f[4]=f2bf(hi.x); f[5]=f2bf(hi.y); f[6]=f2bf(hi.z); f[7]=f2bf(hi.w);
                w2f[kb] = f;
            }
        }

        __syncthreads();   // Gs fully written -> readable by all waves

        // ---- GEMM2: wave owns d-tile [16wid,16wid+16) over K=256 ----
        // swapped operands: D[d_local=4q+r][token=c]
        f32x4 acc2[2] = {{0.f,0.f,0.f,0.f},{0.f,0.f,0.f,0.f}};
#pragma unroll
        for (int kb = 0; kb < 8; ++kb)
#pragma unroll
            for (int m = 0; m < 2; ++m) {
                bf16x8 a2 = *(const bf16x8*)&Gs[16*m + c][kb*32 + q*8];
                acc2[m] = __builtin_amdgcn_mfma_f32_16x16x32_bf16(w2f[kb], a2, acc2[m], 0, 0, 0);
            }

        // ---- epilogue: float4 out[row0+16m+c][16wid+4q..+3]; R loaded here
        //      (TLP hides the latency at this occupancy) ----
#pragma unroll
        for (int m = 0; m < 2; ++m) {
            const size_t off = (size_t)(row0 + 16*m + c) * 64 + 16*wid + 4*q;
            const float4 r4 = *(const float4*)(R + off);
            float4 o;
            o.x = acc2[m][0] + b2q.x + r4.x;
            o.y = acc2[m][1] + b2q.y + r4.y;
            o.z = acc2[m][2] + b2q.z + r4.z;
            o.w = acc2[m][3] + b2q.w + r4.w;
            *(float4*)(out + off) = o;
        }

        if (it + 1 < TILES) __syncthreads();   // Gs WAR across tiles
    }
}

extern "C" void kernel_launch(void* const* d_in, const int* in_sizes, int n_in,
                              void* d_out, int out_size, void* d_ws, size_t ws_size,
                              hipStream_t stream) {
    const float* X  = (const float*)d_in[0];
    const float* R  = (const float*)d_in[1];
    const float* W1 = (const float*)d_in[2];
    const float* b1 = (const float*)d_in[3];
    const float* W2 = (const float*)d_in[4];
    const float* b2 = (const float*)d_in[5];
    float* out = (float*)d_out;
    (void)in_sizes; (void)n_in; (void)out_size;

    if (ws_size >= 65536) {
        short* wsb = (short*)d_ws;
        cvt_weights<<<32, 256, 0, stream>>>(W1, W2, wsb);
        bloom_mlp<true><<<NBLK, 256, 0, stream>>>(X, R, W1, b1, W2, b2, wsb, out);
    } else {
        bloom_mlp<false><<<NBLK, 256, 0, stream>>>(X, R, W1, b1, W2, b2, nullptr, out);
    }
}

// Round 6
// 78.037 us; speedup vs baseline: 2.3265x; 2.3265x over previous
//
#include <hip/hip_runtime.h>
#include <hip/hip_bf16.h>

// Bloom MLP fused: h=X@W1^T+b1; g=gelu_tanh(h); out=g@W2^T+b2+residual
// X:[262144,64] f32, W1:[256,64], W2:[64,256], out:[262144,64] f32.
//
// Round 6: round-4 register plan (w1f+w2f resident, ~64 VGPR, NO tight
// launch-bounds -- round 5's (256,6) forced 40 VGPR and spilled weights to
// scratch: FETCH 66->197MB, WRITE 65->286MB, 181us) + round-5 LDS shrink
// (Gs[32][264] = 16.9KB -> 8 blocks/CU by wave slots instead of 4 by LDS).
// TILES=4, grid 2048.

typedef __attribute__((ext_vector_type(8))) short bf16x8;   // MFMA A/B frag
typedef __attribute__((ext_vector_type(4))) float f32x4;    // MFMA C/D frag
typedef __attribute__((ext_vector_type(4))) short short4v;  // packed 4x bf16

#define NBLK  2048
#define TILES 4      // 2048 blocks * 4 tiles * 32 tokens = 262144

__device__ __forceinline__ short f2bf(float x) {
    union { __hip_bfloat16 h; short s; } u;
    u.h = __float2bfloat16(x);      // compiler pairs into v_cvt_pk_bf16_f32
    return u.s;
}

__device__ __forceinline__ float bloom_gelu(float x) {
    // 0.5*x*(1+tanh(0.79788456*(x+0.044715*x^3))) = x*(1 - 1/(e^{2u}+1))
    // 2u*log2(e) = 2.30220842*x + 0.10294325*x^3  -> v_exp_f32 (2^x) direct
    float x2 = x * x;
    float t1 = __builtin_fmaf(0.10294325f, x2, 2.30220842f);
    float e  = __builtin_exp2f(x * t1);
    float r  = __builtin_amdgcn_rcpf(e + 1.0f);
    return x - x * r;
}

// ---- pre-pass: convert W1 (16384 f32) then W2 (16384 f32) to bf16 in ws ----
__global__ __launch_bounds__(256) void cvt_weights(
    const float* __restrict__ W1, const float* __restrict__ W2,
    short* __restrict__ wsb)
{
    const int i4 = (blockIdx.x * 256 + threadIdx.x) * 4;   // 0..32764, step 4
    const float* src = (i4 < 16384) ? (W1 + i4) : (W2 + (i4 - 16384));
    float4 v = *(const float4*)src;
    short4v o;
    o[0] = f2bf(v.x); o[1] = f2bf(v.y); o[2] = f2bf(v.z); o[3] = f2bf(v.w);
    *(short4v*)(wsb + i4) = o;
}

template<bool PRE>
__global__ __launch_bounds__(256, 4) void bloom_mlp(
    const float* __restrict__ X,  const float* __restrict__ R,
    const float* __restrict__ W1, const float* __restrict__ b1,
    const float* __restrict__ W2, const float* __restrict__ b2,
    const short* __restrict__ Wb, float* __restrict__ out)
{
    // G[token][f] bf16, 32 tokens, row stride 264 (528B): ds_write_b64 at
    // 4 acc/bank, ds_read_b128 at 8 acc/bank -- both the width minimum.
    __shared__ __align__(16) short Gs[32][264];

    const int tid  = threadIdx.x;
    const int wid  = tid >> 6;      // wave 0..3
    const int lane = tid & 63;
    const int q    = lane >> 4;     // 0..3
    const int c    = lane & 15;     // 0..15
    const int f0   = wid << 6;      // GEMM1 f-slice base

    // ---- weight fragments, register-resident across all tiles (~64 VGPR) ----
    bf16x8 w1f[4][2];   // GEMM1 A-op: lane holds W1[f0+16t+c][kb*32+q*8..+7]
    bf16x8 w2f[8];      // GEMM2 A-op: lane holds W2[16wid+c][kb*32+q*8..+7]
    if constexpr (PRE) {
        const short* W1b = Wb;
        const short* W2b = Wb + 16384;
#pragma unroll
        for (int t = 0; t < 4; ++t)
#pragma unroll
            for (int kb = 0; kb < 2; ++kb)
                w1f[t][kb] = *(const bf16x8*)&W1b[(f0 + 16*t + c) * 64 + kb*32 + q*8];
#pragma unroll
        for (int kb = 0; kb < 8; ++kb)
            w2f[kb] = *(const bf16x8*)&W2b[(16*wid + c) * 256 + kb*32 + q*8];
    } else {
#pragma unroll
        for (int t = 0; t < 4; ++t)
#pragma unroll
            for (int kb = 0; kb < 2; ++kb) {
                const float* p = W1 + (size_t)(f0 + 16*t + c) * 64 + kb*32 + q*8;
                float4 lo = *(const float4*)p, hi = *(const float4*)(p + 4);
                bf16x8 f;
                f[0]=f2bf(lo.x); f[1]=f2bf(lo.y); f[2]=f2bf(lo.z); f[3]=f2bf(lo.w);
                f[4]=f2bf(hi.x); f[5]=f2bf(hi.y); f[6]=f2bf(hi.z); f[7]=f2bf(hi.w);
                w1f[t][kb] = f;
            }
#pragma unroll
        for (int kb = 0; kb < 8; ++kb) {
            const float* p = W2 + (size_t)(16*wid + c) * 256 + kb*32 + q*8;
            float4 lo = *(const float4*)p, hi = *(const float4*)(p + 4);
            bf16x8 f;
            f[0]=f2bf(lo.x); f[1]=f2bf(lo.y); f[2]=f2bf(lo.z); f[3]=f2bf(lo.w);
            f[4]=f2bf(hi.x); f[5]=f2bf(hi.y); f[6]=f2bf(hi.z); f[7]=f2bf(hi.w);
            w2f[kb] = f;
        }
    }

    const float4 b2q = *(const float4*)(b2 + 16*wid + 4*q);

    for (int it = 0; it < TILES; ++it) {
        const int row0 = (blockIdx.x * TILES + it) << 5;   // 32 tokens/tile

        // ---- GEMM1 + GELU -> Gs (m = 2 token sub-tiles of 16) ----
#pragma unroll
        for (int m = 0; m < 2; ++m) {
            bf16x8 a1[2];   // B-op: lane holds X[row0+16m+c][kb*32+q*8..+7]
#pragma unroll
            for (int kb = 0; kb < 2; ++kb) {
                const float* p = X + (size_t)(row0 + 16*m + c) * 64 + kb*32 + q*8;
                float4 lo = *(const float4*)p, hi = *(const float4*)(p + 4);
                bf16x8 f;
                f[0]=f2bf(lo.x); f[1]=f2bf(lo.y); f[2]=f2bf(lo.z); f[3]=f2bf(lo.w);
                f[4]=f2bf(hi.x); f[5]=f2bf(hi.y); f[6]=f2bf(hi.z); f[7]=f2bf(hi.w);
                a1[kb] = f;
            }
            // D[f_local=4q+r][token=c] per f-tile t
#pragma unroll
            for (int t = 0; t < 4; ++t) {
                const float4 b1q = *(const float4*)(b1 + f0 + 16*t + 4*q);
                f32x4 acc = {0.f, 0.f, 0.f, 0.f};
                acc = __builtin_amdgcn_mfma_f32_16x16x32_bf16(w1f[t][0], a1[0], acc, 0, 0, 0);
                acc = __builtin_amdgcn_mfma_f32_16x16x32_bf16(w1f[t][1], a1[1], acc, 0, 0, 0);
                short4v g;
#pragma unroll
                for (int r = 0; r < 4; ++r)
                    g[r] = f2bf(bloom_gelu(acc[r] + b1q[r]));
                *(short4v*)&Gs[16*m + c][f0 + 16*t + 4*q] = g;   // 8B packed
            }
        }

        __syncthreads();   // Gs fully written -> readable by all waves

        // ---- GEMM2: wave owns d-tile [16wid,16wid+16) over K=256 ----
        // swapped operands: D[d_local=4q+r][token=c]
        f32x4 acc2[2] = {{0.f,0.f,0.f,0.f},{0.f,0.f,0.f,0.f}};
#pragma unroll
        for (int kb = 0; kb < 8; ++kb)
#pragma unroll
            for (int m = 0; m < 2; ++m) {
                bf16x8 a2 = *(const bf16x8*)&Gs[16*m + c][kb*32 + q*8];
                acc2[m] = __builtin_amdgcn_mfma_f32_16x16x32_bf16(w2f[kb], a2, acc2[m], 0, 0, 0);
            }

        // ---- epilogue: float4 out[row0+16m+c][16wid+4q..+3]; R loaded here
        //      (TLP hides the latency at this occupancy) ----
#pragma unroll
        for (int m = 0; m < 2; ++m) {
            const size_t off = (size_t)(row0 + 16*m + c) * 64 + 16*wid + 4*q;
            const float4 r4 = *(const float4*)(R + off);
            float4 o;
            o.x = acc2[m][0] + b2q.x + r4.x;
            o.y = acc2[m][1] + b2q.y + r4.y;
            o.z = acc2[m][2] + b2q.z + r4.z;
            o.w = acc2[m][3] + b2q.w + r4.w;
            *(float4*)(out + off) = o;
        }

        if (it + 1 < TILES) __syncthreads();   // Gs WAR across tiles
    }
}

extern "C" void kernel_launch(void* const* d_in, const int* in_sizes, int n_in,
                              void* d_out, int out_size, void* d_ws, size_t ws_size,
                              hipStream_t stream) {
    const float* X  = (const float*)d_in[0];
    const float* R  = (const float*)d_in[1];
    const float* W1 = (const float*)d_in[2];
    const float* b1 = (const float*)d_in[3];
    const float* W2 = (const float*)d_in[4];
    const float* b2 = (const float*)d_in[5];
    float* out = (float*)d_out;
    (void)in_sizes; (void)n_in; (void)out_size;

    if (ws_size >= 65536) {
        short* wsb = (short*)d_ws;
        cvt_weights<<<32, 256, 0, stream>>>(W1, W2, wsb);
        bloom_mlp<true><<<NBLK, 256, 0, stream>>>(X, R, W1, b1, W2, b2, wsb, out);
    } else {
        bloom_mlp<false><<<NBLK, 256, 0, stream>>>(X, R, W1, b1, W2, b2, nullptr, out);
    }
}